// Round 2
// baseline (19804.662 us; speedup 1.0000x reference)
//
#include <hip/hip_runtime.h>
#include <hip/hip_cooperative_groups.h>

namespace cg = cooperative_groups;

#define B_ 32
#define T_ 250
#define D_ 3424
#define S_ 4000
#define E_ 200000
#define NEGV (-1e30f)
#define LOGLEAK (-2.3025850929940457f)   // log(0.1)

__device__ __forceinline__ float logaddexpf_(float a, float b) {
  float mx = fmaxf(a, b);
  float mn = fminf(a, b);
  return mx + log1pf(__expf(mn - mx));
}

// ---------------- preprocessing kernels ----------------

__global__ void init_kernel(float* __restrict__ buf0, float* __restrict__ totsumP,
                            float* __restrict__ finalsum, float* __restrict__ numsum,
                            int* __restrict__ indeg) {
  int i = blockIdx.x * blockDim.x + threadIdx.x;
  if (i < S_ * B_) buf0[i] = (i < B_) ? 0.f : NEGV;            // alpha0: state 0 = 0, rest NEG
  if (i < (T_ + 1) * 1024) totsumP[i] = (i < 1024 && (i & 31) == 0) ? 1.f : 0.f; // totsum[0][b]=1 -> log=0
  if (i < 1024) finalsum[i] = 0.f;
  if (i == 0) numsum[0] = 0.f;
  if (i < S_) indeg[i] = 0;
}

__global__ void hist_kernel(const int* __restrict__ edst, int* __restrict__ indeg) {
  int e = blockIdx.x * blockDim.x + threadIdx.x;
  if (e < E_) atomicAdd(&indeg[edst[e]], 1);
}

__global__ void scan_kernel(const int* __restrict__ indeg, int* __restrict__ row_off,
                            int* __restrict__ fill) {
  __shared__ int part[1024];
  int tid = threadIdx.x;
  int base = tid * 4;
  int lsum = 0;
  for (int k = 0; k < 4; ++k) {
    int idx = base + k;
    if (idx < S_) lsum += indeg[idx];
  }
  part[tid] = lsum;
  __syncthreads();
  if (tid == 0) {
    int run = 0;
    for (int i = 0; i < 1024; ++i) { int v = part[i]; part[i] = run; run += v; }
  }
  __syncthreads();
  int off = part[tid];
  for (int k = 0; k < 4; ++k) {
    int idx = base + k;
    if (idx < S_) {
      row_off[idx] = off;
      fill[idx] = off;
      off += indeg[idx];
    } else if (idx == S_) {
      row_off[S_] = off;
    }
  }
}

__global__ void scatter_kernel(const int* __restrict__ esrc, const int* __restrict__ edst,
                               const int* __restrict__ epdf, const float* __restrict__ ew,
                               int* __restrict__ fill, int4* __restrict__ epack) {
  int e = blockIdx.x * blockDim.x + threadIdx.x;
  if (e < E_) {
    int slot = atomicAdd(&fill[edst[e]], 1);
    epack[slot] = make_int4(esrc[e], epdf[e], __float_as_int(ew[e]), 0);
  }
}

// x [B,T,D] -> xT [T,D,B]
__global__ void transpose_kernel(const float* __restrict__ x, float* __restrict__ xT) {
  __shared__ float tile[32][33];
  int t  = blockIdx.y;
  int d0 = blockIdx.x * 32;
  int lx = threadIdx.x & 31;
  int ly = threadIdx.x >> 5;   // 0..7
  for (int bb = ly; bb < 32; bb += 8) {
    int d = d0 + lx;
    tile[bb][lx] = (d < D_) ? x[((size_t)bb * T_ + t) * D_ + d] : 0.f;
  }
  __syncthreads();
  for (int dd = ly; dd < 32; dd += 8) {
    int d = d0 + dd;
    if (d < D_) xT[((size_t)t * D_ + d) * B_ + lx] = tile[lx][dd];
  }
}

__global__ void num_kernel(const float* __restrict__ x, const int* __restrict__ target,
                           float* __restrict__ numsum) {
  int i = blockIdx.x * blockDim.x + threadIdx.x;   // over B*T
  float v = 0.f;
  if (i < B_ * T_) {
    int tgt = target[i];
    float xv = x[(size_t)i * D_ + tgt];
    v = fminf(fmaxf(xv, -30.f), 30.f);
  }
  for (int off = 32; off; off >>= 1) v += __shfl_down(v, off);
  if ((threadIdx.x & 63) == 0) atomicAdd(numsum, v);
}

// ---------------- main cooperative chain kernel ----------------
// grid: 500 blocks x 256 threads; block handles 8 states (j=tid>>5), lane = batch b (tid&31)

__global__ __launch_bounds__(256, 2) void chain_kernel(
    const float* __restrict__ xsrc, const int4* __restrict__ epack,
    const int* __restrict__ row_off, const float* __restrict__ flw,
    float* __restrict__ buf, float* __restrict__ totsumP,
    float* __restrict__ finalsum, const float* __restrict__ numsum,
    float* __restrict__ out, int use_xt) {
  cg::grid_group grid = cg::this_grid();
  const int b = threadIdx.x & 31;
  const int j = threadIdx.x >> 5;
  const int s = blockIdx.x * 8 + j;          // 500*8 = 4000 exactly
  const int beg = row_off[s];
  const int end = row_off[s + 1];
  const int wv = threadIdx.x >> 6;
  __shared__ float wsum[4][32];
  float logzacc = 0.f;                       // sum of tot_0 .. tot_{t-2} at iter t

  for (int t = 0; t < T_; ++t) {
    const float* __restrict__ prev = buf + (size_t)(t & 1) * S_ * B_;
    float* __restrict__ next = buf + (size_t)((t + 1) & 1) * S_ * B_;
    const float totprev = logf(totsumP[t * 1024 + b * 32]);
    if (t > 0) logzacc += totprev;
    // leak applies only to state 0 (init_log==NEG elsewhere is a fp32 no-op);
    // hoist it out of the edge loop: adjusted alpha for src==0, this (t,b).
    const float prev0 = prev[b];
    const float a0rep = (t > 0) ? logaddexpf_(prev0, LOGLEAK + totprev) : prev0;
    const float* __restrict__ xb = use_xt ? (xsrc + (size_t)t * D_ * B_ + b)
                                          : (xsrc + ((size_t)b * T_ + t) * D_);
    const int xstr = use_xt ? B_ : 1;

    float m0 = -INFINITY, s0 = 0.f, m1 = -INFINITY, s1 = 0.f;
    int i = beg;
    for (; i + 1 < end; i += 2) {
      int4 e0 = epack[i];
      int4 e1 = epack[i + 1];
      float a0 = (e0.x == 0) ? a0rep : prev[e0.x * B_ + b];
      float a1 = (e1.x == 0) ? a0rep : prev[e1.x * B_ + b];
      float v0 = a0 - totprev + __int_as_float(e0.z) + xb[(size_t)e0.y * xstr];
      float v1 = a1 - totprev + __int_as_float(e1.z) + xb[(size_t)e1.y * xstr];
      float nm0 = fmaxf(m0, v0);
      s0 = s0 * __expf(m0 - nm0) + __expf(v0 - nm0);
      m0 = nm0;
      float nm1 = fmaxf(m1, v1);
      s1 = s1 * __expf(m1 - nm1) + __expf(v1 - nm1);
      m1 = nm1;
    }
    if (i < end) {
      int4 e0 = epack[i];
      float a0 = (e0.x == 0) ? a0rep : prev[e0.x * B_ + b];
      float v0 = a0 - totprev + __int_as_float(e0.z) + xb[(size_t)e0.y * xstr];
      float nm0 = fmaxf(m0, v0);
      s0 = s0 * __expf(m0 - nm0) + __expf(v0 - nm0);
      m0 = nm0;
    }
    if (m1 > -INFINITY) {            // merge acc1 into acc0 (guard -inf - -inf = NaN)
      float mm = fmaxf(m0, m1);
      s0 = s0 * __expf(m0 - mm) + s1 * __expf(m1 - mm);
      m0 = mm;
    }

    float nv = (s0 > 0.f) ? (m0 + __logf(s0)) : NEGV;   // pre-leak new[s,b]
    next[s * B_ + b] = nv;
    float ev = (s0 > 0.f) ? s0 * __expf(m0) : 0.f;      // exp(nv), 0 on underflow

    // block-level reduction of exp(new) over the 8 states, then 1 atomic per (block,b)
    float evs = ev + __shfl_xor(ev, 32);
    if ((threadIdx.x & 63) < 32) wsum[wv][b] = evs;
    __syncthreads();
    if (threadIdx.x < 32) {
      float tt = wsum[0][b] + wsum[1][b] + wsum[2][b] + wsum[3][b];
      atomicAdd(&totsumP[(t + 1) * 1024 + b * 32], tt);
    }
    grid.sync();
  }

  // ----- epilogue: final = lse_s(alphaT + final_logw), then loss -----
  {
    const float totlast = logf(totsumP[T_ * 1024 + b * 32]);
    const float logz = logzacc + totlast +
                       ((T_ > 1) ? logf(totsumP[(T_ - 1) * 1024 + b * 32]) : 0.f);
    // logzacc has tot_0..tot_{T-3}; add tot_{T-2} (read at t=T-1 but added only
    // for t>0 iterations up to T-1 => logzacc covers tot_0..tot_{T-2} already?
    // No: at iter t we add totprev=tot_{t-1}; last add is at t=T-1 adding tot_{T-2}.
    // So logzacc = tot_0..tot_{T-2}; full logz = logzacc + tot_{T-1} = logzacc+totlast.
    const float logz_fix = logzacc + totlast;
    const float* __restrict__ last = buf + (size_t)(T_ & 1) * S_ * B_;
    float v = last[s * B_ + b];
    if (s == 0) v = logaddexpf_(v, LOGLEAK + totlast);
    v = v - totlast + flw[s];
    float ev = __expf(v);
    float evs = ev + __shfl_xor(ev, 32);
    if ((threadIdx.x & 63) < 32) wsum[wv][b] = evs;
    __syncthreads();
    if (threadIdx.x < 32) {
      float tt = wsum[0][b] + wsum[1][b] + wsum[2][b] + wsum[3][b];
      atomicAdd(&finalsum[b * 32], tt);
    }
    grid.sync();
    (void)logz;
    if (blockIdx.x == 0 && threadIdx.x < 32) {
      float den_b = logz_fix + logf(finalsum[b * 32]);
      for (int off = 16; off; off >>= 1) den_b += __shfl_down(den_b, off);
      if (threadIdx.x == 0) {
        out[0] = -(numsum[0] - den_b) / (float)(B_ * T_);
      }
    }
  }
}

// ---------------- launcher ----------------

extern "C" void kernel_launch(void* const* d_in, const int* in_sizes, int n_in,
                              void* d_out, int out_size, void* d_ws, size_t ws_size,
                              hipStream_t stream) {
  const float* x      = (const float*)d_in[0];
  const int*   target = (const int*)d_in[1];
  const int*   esrc   = (const int*)d_in[2];
  const int*   edst   = (const int*)d_in[3];
  const int*   epdf   = (const int*)d_in[4];
  const float* ew     = (const float*)d_in[5];
  const float* flw    = (const float*)d_in[6];
  float* out = (float*)d_out;

  char* base = (char*)d_ws;
  size_t off = 0;
  auto take = [&](size_t bytes) -> char* {
    char* r = base + off;
    off += (bytes + 255) & ~(size_t)255;
    return r;
  };
  float* buf      = (float*)take((size_t)2 * S_ * B_ * 4);        // double-buffered alpha (raw)
  float* totsumP  = (float*)take((size_t)(T_ + 1) * 1024 * 4);    // sum(exp(new_t)), line-padded per b
  float* finalsum = (float*)take(1024 * 4);
  float* numsum   = (float*)take(256);
  int*   indeg    = (int*)take((size_t)S_ * 4);
  int*   row_off  = (int*)take((size_t)(S_ + 1) * 4);
  int*   fill     = (int*)take((size_t)S_ * 4);
  int4*  epack    = (int4*)take((size_t)E_ * 16);                 // CSR-by-dst packed arcs
  size_t xt_bytes = (size_t)T_ * D_ * B_ * 4;
  int use_xt = (off + xt_bytes <= ws_size) ? 1 : 0;               // deterministic per ws_size
  float* xT = (float*)take(xt_bytes);
  const float* xsrc = use_xt ? (const float*)xT : x;

  hipLaunchKernelGGL(init_kernel, dim3(((T_ + 1) * 1024 + 255) / 256), dim3(256), 0, stream,
                     buf, totsumP, finalsum, numsum, indeg);
  hipLaunchKernelGGL(hist_kernel, dim3((E_ + 255) / 256), dim3(256), 0, stream, edst, indeg);
  hipLaunchKernelGGL(scan_kernel, dim3(1), dim3(1024), 0, stream, indeg, row_off, fill);
  hipLaunchKernelGGL(scatter_kernel, dim3((E_ + 255) / 256), dim3(256), 0, stream,
                     esrc, edst, epdf, ew, fill, epack);
  if (use_xt) {
    hipLaunchKernelGGL(transpose_kernel, dim3(D_ / 32, T_), dim3(256), 0, stream, x, xT);
  }
  hipLaunchKernelGGL(num_kernel, dim3((B_ * T_ + 255) / 256), dim3(256), 0, stream,
                     x, target, numsum);

  int use_xt_arg = use_xt;
  void* args[] = {(void*)&xsrc, (void*)&epack, (void*)&row_off, (void*)&flw,
                  (void*)&buf, (void*)&totsumP, (void*)&finalsum, (void*)&numsum,
                  (void*)&out, (void*)&use_xt_arg};
  hipLaunchCooperativeKernel((void*)chain_kernel, dim3(500), dim3(256), args, 0, stream);
}

// Round 7
// 18673.595 us; speedup vs baseline: 1.0606x; 1.0606x over previous
//
#include <hip/hip_runtime.h>
#include <hip/hip_cooperative_groups.h>

namespace cg = cooperative_groups;

#define B_ 32
#define T_ 250
#define D_ 3424
#define S_ 4000
#define E_ 200000
#define NEGV (-1e30f)
#define LOGLEAK (-2.3025850929940457f)   // log(0.1)

#define NBLK 500           // chain blocks (PROVEN cooperative envelope from round 2)
#define SPB 8              // states per block, one per half-wave
#define LDSCAP 768         // staged edges per block (mean ~400, huge margin) + global fallback
#define NBUCK 16           // tot atomic buckets

__device__ __forceinline__ float logaddexpf_(float a, float b) {
  float mx = fmaxf(a, b);
  float mn = fminf(a, b);
  return mx + log1pf(__expf(mn - mx));
}

// ---------------- preprocessing kernels ----------------

__global__ void init_kernel(float* __restrict__ buf0, float* __restrict__ totsumP,
                            float* __restrict__ finalsum, float* __restrict__ numsum,
                            int* __restrict__ indeg) {
  int i = blockIdx.x * blockDim.x + threadIdx.x;
  if (i < S_ * B_) buf0[i] = (i < B_) ? 0.f : NEGV;            // alpha0: state 0 = 0, rest NEG
  // totsum layout: [T+1][B][NBUCK]; t=0 must sum to 1 per b -> bucket 0 = 1
  if (i < (T_ + 1) * B_ * NBUCK) totsumP[i] = (i < B_ * NBUCK && (i % NBUCK) == 0) ? 1.f : 0.f;
  if (i < 1024) finalsum[i] = 0.f;
  if (i == 0) numsum[0] = 0.f;
  if (i < S_) indeg[i] = 0;
}

__global__ void hist_kernel(const int* __restrict__ edst, int* __restrict__ indeg) {
  int e = blockIdx.x * blockDim.x + threadIdx.x;
  if (e < E_) atomicAdd(&indeg[edst[e]], 1);
}

__global__ void scan_kernel(const int* __restrict__ indeg, int* __restrict__ row_off,
                            int* __restrict__ fill) {
  __shared__ int part[1024];
  int tid = threadIdx.x;
  int base = tid * 4;
  int lsum = 0;
  for (int k = 0; k < 4; ++k) {
    int idx = base + k;
    if (idx < S_) lsum += indeg[idx];
  }
  part[tid] = lsum;
  __syncthreads();
  if (tid == 0) {
    int run = 0;
    for (int i = 0; i < 1024; ++i) { int v = part[i]; part[i] = run; run += v; }
  }
  __syncthreads();
  int off = part[tid];
  for (int k = 0; k < 4; ++k) {
    int idx = base + k;
    if (idx < S_) {
      row_off[idx] = off;
      fill[idx] = off;
      off += indeg[idx];
    } else if (idx == S_) {
      row_off[S_] = off;
    }
  }
}

__global__ void scatter_kernel(const int* __restrict__ esrc, const int* __restrict__ edst,
                               const int* __restrict__ epdf, const float* __restrict__ ew,
                               int* __restrict__ fill, int4* __restrict__ epack) {
  int e = blockIdx.x * blockDim.x + threadIdx.x;
  if (e < E_) {
    int slot = atomicAdd(&fill[edst[e]], 1);
    epack[slot] = make_int4(esrc[e], epdf[e], __float_as_int(ew[e]), 0);
  }
}

// x [B,T,D] -> xT [T,D,B]
__global__ void transpose_kernel(const float* __restrict__ x, float* __restrict__ xT) {
  __shared__ float tile[32][33];
  int t  = blockIdx.y;
  int d0 = blockIdx.x * 32;
  int lx = threadIdx.x & 31;
  int ly = threadIdx.x >> 5;   // 0..7
  for (int bb = ly; bb < 32; bb += 8) {
    int d = d0 + lx;
    tile[bb][lx] = (d < D_) ? x[((size_t)bb * T_ + t) * D_ + d] : 0.f;
  }
  __syncthreads();
  for (int dd = ly; dd < 32; dd += 8) {
    int d = d0 + dd;
    if (d < D_) xT[((size_t)t * D_ + d) * B_ + lx] = tile[lx][dd];
  }
}

__global__ void num_kernel(const float* __restrict__ x, const int* __restrict__ target,
                           float* __restrict__ numsum) {
  int i = blockIdx.x * blockDim.x + threadIdx.x;   // over B*T
  float v = 0.f;
  if (i < B_ * T_) {
    int tgt = target[i];
    float xv = x[(size_t)i * D_ + tgt];
    v = fminf(fmaxf(xv, -30.f), 30.f);
  }
  for (int off = 32; off; off >>= 1) v += __shfl_down(v, off);
  if ((threadIdx.x & 63) == 0) atomicAdd(numsum, v);
}

// ---------------- main cooperative chain kernel ----------------
// ROUND-2-PROVEN ENVELOPE: 500 blocks x 256 threads, launch_bounds (256,2).
// Half-wave j = tid>>5 (0..7) owns state s = blk*8 + j; lane b = tid&31.
// Interior changes only: LDS edge staging, unroll-4 ILP, bucketed tot atomics.

__global__ __launch_bounds__(256, 2) void chain_kernel(
    const float* __restrict__ xsrc, const int4* __restrict__ epack,
    const int* __restrict__ row_off, const float* __restrict__ flw,
    float* __restrict__ buf, float* __restrict__ totsumP,
    float* __restrict__ finalsum, const float* __restrict__ numsum,
    float* __restrict__ out, int use_xt) {
  cg::grid_group grid = cg::this_grid();
  const int b  = threadIdx.x & 31;
  const int j  = threadIdx.x >> 5;                 // 0..7  (half-wave -> state)
  const int s  = blockIdx.x * SPB + j;             // 500*8 = 4000 exactly
  const int wv = threadIdx.x >> 6;                 // 0..3  (wave id)
  const int g  = blockIdx.x & (NBUCK - 1);         // tot atomic bucket

  __shared__ int4  lds_e[LDSCAP];
  __shared__ float wsum[4][32];

  // ---- stage this block's edge slice into LDS once (time-invariant) ----
  const int blkBeg = row_off[blockIdx.x * SPB];
  const int blkCnt = row_off[blockIdx.x * SPB + SPB] - blkBeg;
  for (int k = threadIdx.x; k < blkCnt && k < LDSCAP; k += 256)
    lds_e[k] = epack[blkBeg + k];

  const int beg = row_off[s];
  const int end = row_off[s + 1];

  __syncthreads();

  float logzacc = 0.f;                             // sum of tot idx 1..t-1

#define EDGE(I) (((I) - blkBeg < LDSCAP) ? lds_e[(I) - blkBeg] : epack[(I)])

  for (int t = 0; t < T_; ++t) {
    const float* __restrict__ prev = buf + (size_t)(t & 1) * S_ * B_;
    float* __restrict__ next = buf + (size_t)((t + 1) & 1) * S_ * B_;

    // tot_{t-1} = log(sum of 16 buckets)
    const float4* tp = (const float4*)(totsumP + (size_t)t * B_ * NBUCK + b * NBUCK);
    float4 q0 = tp[0], q1 = tp[1], q2 = tp[2], q3 = tp[3];
    float tsum = (q0.x + q0.y + q0.z + q0.w) + (q1.x + q1.y + q1.z + q1.w) +
                 (q2.x + q2.y + q2.z + q2.w) + (q3.x + q3.y + q3.z + q3.w);
    const float totprev = logf(tsum);
    if (t > 0) logzacc += totprev;

    // leak only affects state 0 (init_log == NEG elsewhere is an fp32 no-op)
    const float prev0 = prev[b];
    const float a0rep = (t > 0) ? logaddexpf_(prev0, LOGLEAK + totprev) : prev0;

    const float* __restrict__ xb = use_xt ? (xsrc + (size_t)t * D_ * B_ + b)
                                          : (xsrc + ((size_t)b * T_ + t) * D_);
    const int xstr = use_xt ? B_ : 1;

    float m0 = -INFINITY, s0 = 0.f, m1 = -INFINITY, s1 = 0.f;
    int i = beg;
    for (; i + 3 < end; i += 4) {
      int4 e0 = EDGE(i);
      int4 e1 = EDGE(i + 1);
      int4 e2 = EDGE(i + 2);
      int4 e3 = EDGE(i + 3);
      float a0 = (e0.x == 0) ? a0rep : prev[e0.x * B_ + b];
      float a1 = (e1.x == 0) ? a0rep : prev[e1.x * B_ + b];
      float a2 = (e2.x == 0) ? a0rep : prev[e2.x * B_ + b];
      float a3 = (e3.x == 0) ? a0rep : prev[e3.x * B_ + b];
      float x0 = xb[(size_t)e0.y * xstr];
      float x1 = xb[(size_t)e1.y * xstr];
      float x2 = xb[(size_t)e2.y * xstr];
      float x3 = xb[(size_t)e3.y * xstr];
      float v0 = a0 - totprev + __int_as_float(e0.z) + x0;
      float v1 = a1 - totprev + __int_as_float(e1.z) + x1;
      float v2 = a2 - totprev + __int_as_float(e2.z) + x2;
      float v3 = a3 - totprev + __int_as_float(e3.z) + x3;
      float nm0 = fmaxf(m0, v0);
      s0 = s0 * __expf(m0 - nm0) + __expf(v0 - nm0);
      m0 = nm0;
      float nm1 = fmaxf(m1, v2);
      s1 = s1 * __expf(m1 - nm1) + __expf(v2 - nm1);
      m1 = nm1;
      nm0 = fmaxf(m0, v1);
      s0 = s0 * __expf(m0 - nm0) + __expf(v1 - nm0);
      m0 = nm0;
      nm1 = fmaxf(m1, v3);
      s1 = s1 * __expf(m1 - nm1) + __expf(v3 - nm1);
      m1 = nm1;
    }
    for (; i < end; ++i) {
      int4 e0 = EDGE(i);
      float a0 = (e0.x == 0) ? a0rep : prev[e0.x * B_ + b];
      float v0 = a0 - totprev + __int_as_float(e0.z) + xb[(size_t)e0.y * xstr];
      float nm0 = fmaxf(m0, v0);
      s0 = s0 * __expf(m0 - nm0) + __expf(v0 - nm0);
      m0 = nm0;
    }
    // merge acc1 into acc0 (guard -inf - -inf = NaN)
    if (m1 > -INFINITY) {
      float mm = fmaxf(m0, m1);
      s0 = s0 * __expf(m0 - mm) + s1 * __expf(m1 - mm);
      m0 = mm;
    }

    float nv = (s0 > 0.f) ? (m0 + __logf(s0)) : NEGV;   // pre-leak new[s,b]
    next[s * B_ + b] = nv;
    float ev = (s0 > 0.f) ? s0 * __expf(m0) : 0.f;      // exp(nv), 0 on underflow

    // reduce exp(new) over the block's 8 states, then 1 bucketed atomic per (block,b)
    float evs = ev + __shfl_xor(ev, 32);                // merge the wave's 2 states
    if ((threadIdx.x & 63) < 32) wsum[wv][b] = evs;
    __syncthreads();
    if (threadIdx.x < 32) {
      float tt = wsum[0][b] + wsum[1][b] + wsum[2][b] + wsum[3][b];
      atomicAdd(&totsumP[(size_t)(t + 1) * B_ * NBUCK + b * NBUCK + g], tt);
    }
    grid.sync();
  }

  // ----- epilogue: final = lse_s(alphaT + final_logw), then loss -----
  {
    const float4* tp = (const float4*)(totsumP + (size_t)T_ * B_ * NBUCK + b * NBUCK);
    float4 q0 = tp[0], q1 = tp[1], q2 = tp[2], q3 = tp[3];
    float tsum = (q0.x + q0.y + q0.z + q0.w) + (q1.x + q1.y + q1.z + q1.w) +
                 (q2.x + q2.y + q2.z + q2.w) + (q3.x + q3.y + q3.z + q3.w);
    const float totlast = logf(tsum);
    const float logz = logzacc + totlast;               // tot idx 1..T

    const float* __restrict__ last = buf + (size_t)(T_ & 1) * S_ * B_;
    float v = last[s * B_ + b];
    if (s == 0) v = logaddexpf_(v, LOGLEAK + totlast);
    v = v - totlast + flw[s];
    float ev = __expf(v);
    float evs = ev + __shfl_xor(ev, 32);
    if ((threadIdx.x & 63) < 32) wsum[wv][b] = evs;
    __syncthreads();
    if (threadIdx.x < 32) {
      float tt = wsum[0][b] + wsum[1][b] + wsum[2][b] + wsum[3][b];
      atomicAdd(&finalsum[b * 32], tt);
    }
    grid.sync();
    if (blockIdx.x == 0 && threadIdx.x < 32) {
      float den_b = logz + logf(finalsum[b * 32]);
      for (int off = 16; off; off >>= 1) den_b += __shfl_down(den_b, off);
      if (threadIdx.x == 0) {
        out[0] = -(numsum[0] - den_b) / (float)(B_ * T_);
      }
    }
  }
#undef EDGE
}

// ---------------- launcher ----------------

extern "C" void kernel_launch(void* const* d_in, const int* in_sizes, int n_in,
                              void* d_out, int out_size, void* d_ws, size_t ws_size,
                              hipStream_t stream) {
  const float* x      = (const float*)d_in[0];
  const int*   target = (const int*)d_in[1];
  const int*   esrc   = (const int*)d_in[2];
  const int*   edst   = (const int*)d_in[3];
  const int*   epdf   = (const int*)d_in[4];
  const float* ew     = (const float*)d_in[5];
  const float* flw    = (const float*)d_in[6];
  float* out = (float*)d_out;

  char* base = (char*)d_ws;
  size_t off = 0;
  auto take = [&](size_t bytes) -> char* {
    char* r = base + off;
    off += (bytes + 255) & ~(size_t)255;
    return r;
  };
  float* buf      = (float*)take((size_t)2 * S_ * B_ * 4);          // double-buffered alpha
  float* totsumP  = (float*)take((size_t)(T_ + 1) * B_ * NBUCK * 4);// bucketed sum(exp(new_t))
  float* finalsum = (float*)take(1024 * 4);
  float* numsum   = (float*)take(256);
  int*   indeg    = (int*)take((size_t)S_ * 4);
  int*   row_off  = (int*)take((size_t)(S_ + 1) * 4);
  int*   fill     = (int*)take((size_t)S_ * 4);
  int4*  epack    = (int4*)take((size_t)E_ * 16);                   // CSR-by-dst packed arcs
  size_t xt_bytes = (size_t)T_ * D_ * B_ * 4;
  int use_xt = (off + xt_bytes <= ws_size) ? 1 : 0;                 // deterministic per ws_size
  float* xT = (float*)take(xt_bytes);
  const float* xsrc = use_xt ? (const float*)xT : x;

  int init_n = (T_ + 1) * B_ * NBUCK;
  if (init_n < S_ * B_) init_n = S_ * B_;
  hipLaunchKernelGGL(init_kernel, dim3((init_n + 255) / 256), dim3(256), 0, stream,
                     buf, totsumP, finalsum, numsum, indeg);
  hipLaunchKernelGGL(hist_kernel, dim3((E_ + 255) / 256), dim3(256), 0, stream, edst, indeg);
  hipLaunchKernelGGL(scan_kernel, dim3(1), dim3(1024), 0, stream, indeg, row_off, fill);
  hipLaunchKernelGGL(scatter_kernel, dim3((E_ + 255) / 256), dim3(256), 0, stream,
                     esrc, edst, epdf, ew, fill, epack);
  if (use_xt) {
    hipLaunchKernelGGL(transpose_kernel, dim3(D_ / 32, T_), dim3(256), 0, stream, x, xT);
  }
  hipLaunchKernelGGL(num_kernel, dim3((B_ * T_ + 255) / 256), dim3(256), 0, stream,
                     x, target, numsum);

  int use_xt_arg = use_xt;
  void* args[] = {(void*)&xsrc, (void*)&epack, (void*)&row_off, (void*)&flw,
                  (void*)&buf, (void*)&totsumP, (void*)&finalsum, (void*)&numsum,
                  (void*)&out, (void*)&use_xt_arg};
  hipLaunchCooperativeKernel((void*)chain_kernel, dim3(NBLK), dim3(256), args, 0, stream);
}

// Round 13
// 8792.256 us; speedup vs baseline: 2.2525x; 2.1239x over previous
//
#include <hip/hip_runtime.h>

#define B_ 32
#define T_ 250
#define D_ 3424
#define S_ 4000
#define E_ 200000
#define NEGV (-1e30f)
#define LOGLEAK (-2.3025850929940457f)   // log(0.1)

#define NBLK 1000          // step-kernel blocks; 4 states each (regular launch, no coop limit)
#define SPB 4              // states per block, one per wave; edges split across wave halves
#define NBLK_F 500         // final_kernel blocks (validated geometry)
#define SPB_F 8            // states per block in final_kernel (half-wave per state)
#define NBUCK 16           // tot atomic buckets

__device__ __forceinline__ float logaddexpf_(float a, float b) {
  float mx = fmaxf(a, b);
  float mn = fminf(a, b);
  return mx + log1pf(__expf(mn - mx));
}

// ---------------- preprocessing kernels ----------------

__global__ void init_kernel(float* __restrict__ buf0, float* __restrict__ totsumP,
                            float* __restrict__ finalsum, float* __restrict__ numsum,
                            int* __restrict__ indeg) {
  int i = blockIdx.x * blockDim.x + threadIdx.x;
  if (i < S_ * B_) buf0[i] = (i < B_) ? 0.f : NEGV;            // alpha0: state 0 = 0, rest NEG
  // totsum layout: [T+1][B][NBUCK]; t=0 must sum to 1 per b -> bucket 0 = 1
  if (i < (T_ + 1) * B_ * NBUCK) totsumP[i] = (i < B_ * NBUCK && (i % NBUCK) == 0) ? 1.f : 0.f;
  if (i < 1024) finalsum[i] = 0.f;
  if (i == 0) numsum[0] = 0.f;
  if (i < S_) indeg[i] = 0;
}

__global__ void hist_kernel(const int* __restrict__ edst, int* __restrict__ indeg) {
  int e = blockIdx.x * blockDim.x + threadIdx.x;
  if (e < E_) atomicAdd(&indeg[edst[e]], 1);
}

__global__ void scan_kernel(const int* __restrict__ indeg, int* __restrict__ row_off,
                            int* __restrict__ fill) {
  __shared__ int part[1024];
  int tid = threadIdx.x;
  int base = tid * 4;
  int lsum = 0;
  for (int k = 0; k < 4; ++k) {
    int idx = base + k;
    if (idx < S_) lsum += indeg[idx];
  }
  part[tid] = lsum;
  __syncthreads();
  if (tid == 0) {
    int run = 0;
    for (int i = 0; i < 1024; ++i) { int v = part[i]; part[i] = run; run += v; }
  }
  __syncthreads();
  int off = part[tid];
  for (int k = 0; k < 4; ++k) {
    int idx = base + k;
    if (idx < S_) {
      row_off[idx] = off;
      fill[idx] = off;
      off += indeg[idx];
    } else if (idx == S_) {
      row_off[S_] = off;
    }
  }
}

__global__ void scatter_kernel(const int* __restrict__ esrc, const int* __restrict__ edst,
                               const int* __restrict__ epdf, const float* __restrict__ ew,
                               int* __restrict__ fill, int4* __restrict__ epack) {
  int e = blockIdx.x * blockDim.x + threadIdx.x;
  if (e < E_) {
    int slot = atomicAdd(&fill[edst[e]], 1);
    epack[slot] = make_int4(esrc[e], epdf[e], __float_as_int(ew[e]), 0);
  }
}

// x [B,T,D] -> xT [T,D,B]
__global__ void transpose_kernel(const float* __restrict__ x, float* __restrict__ xT) {
  __shared__ float tile[32][33];
  int t  = blockIdx.y;
  int d0 = blockIdx.x * 32;
  int lx = threadIdx.x & 31;
  int ly = threadIdx.x >> 5;   // 0..7
  for (int bb = ly; bb < 32; bb += 8) {
    int d = d0 + lx;
    tile[bb][lx] = (d < D_) ? x[((size_t)bb * T_ + t) * D_ + d] : 0.f;
  }
  __syncthreads();
  for (int dd = ly; dd < 32; dd += 8) {
    int d = d0 + dd;
    if (d < D_) xT[((size_t)t * D_ + d) * B_ + lx] = tile[lx][dd];
  }
}

__global__ void num_kernel(const float* __restrict__ x, const int* __restrict__ target,
                           float* __restrict__ numsum) {
  int i = blockIdx.x * blockDim.x + threadIdx.x;   // over B*T
  float v = 0.f;
  if (i < B_ * T_) {
    int tgt = target[i];
    float xv = x[(size_t)i * D_ + tgt];
    v = fminf(fmaxf(xv, -30.f), 30.f);
  }
  for (int off = 32; off; off >>= 1) v += __shfl_down(v, off);
  if ((threadIdx.x & 63) == 0) atomicAdd(numsum, v);
}

// ---------------- per-timestep kernel ----------------
// 1000 blocks x 256 threads. Wave wv = tid>>6 owns state s = blk*4 + wv.
// Within the wave: lane = (half<<5) | b; the two halves split the state's edge
// list and merge their online-LSE accumulators via __shfl_xor(..., 32).
// Stream ordering between launches provides the global barrier + cross-XCD visibility.

__global__ __launch_bounds__(256) void step_kernel(
    const float* __restrict__ xsrc, const int4* __restrict__ epack,
    const int* __restrict__ row_off, float* __restrict__ buf,
    float* __restrict__ totsumP, int use_xt, int t) {
  const int lane = threadIdx.x & 63;
  const int b    = lane & 31;
  const int half = lane >> 5;                      // 0..1
  const int wv   = threadIdx.x >> 6;               // 0..3 (wave id)
  const int s    = blockIdx.x * SPB + wv;          // 1000*4 = 4000 exactly
  const int g    = blockIdx.x & (NBUCK - 1);       // tot atomic bucket
  __shared__ float wsum[4][32];

  const float* __restrict__ prev = buf + (size_t)(t & 1) * S_ * B_;
  float* __restrict__ next = buf + (size_t)((t + 1) & 1) * S_ * B_;

  // tot_{t-1} = log(sum of 16 buckets)
  const float4* tp = (const float4*)(totsumP + (size_t)t * B_ * NBUCK + b * NBUCK);
  float4 q0 = tp[0], q1 = tp[1], q2 = tp[2], q3 = tp[3];
  float tsum = (q0.x + q0.y + q0.z + q0.w) + (q1.x + q1.y + q1.z + q1.w) +
               (q2.x + q2.y + q2.z + q2.w) + (q3.x + q3.y + q3.z + q3.w);
  const float totprev = logf(tsum);

  // leak only affects state 0 (init_log == NEG elsewhere is an fp32 no-op)
  const float prev0 = prev[b];
  const float a0rep = (t > 0) ? logaddexpf_(prev0, LOGLEAK + totprev) : prev0;

  const float* __restrict__ xb = use_xt ? (xsrc + (size_t)t * D_ * B_ + b)
                                        : (xsrc + ((size_t)b * T_ + t) * D_);
  const int xstr = use_xt ? B_ : 1;

  // this half's share of the state's edge range
  const int beg = row_off[s];
  const int end = row_off[s + 1];
  const int len = end - beg;
  const int l0  = (len + 1) >> 1;
  const int hb  = beg + (half ? l0 : 0);
  const int he  = half ? end : (beg + l0);

  float m0 = -INFINITY, s0 = 0.f, m1 = -INFINITY, s1 = 0.f;
  int i = hb;
  for (; i + 3 < he; i += 4) {
    int4 e0 = epack[i];
    int4 e1 = epack[i + 1];
    int4 e2 = epack[i + 2];
    int4 e3 = epack[i + 3];
    float a0 = (e0.x == 0) ? a0rep : prev[e0.x * B_ + b];
    float a1 = (e1.x == 0) ? a0rep : prev[e1.x * B_ + b];
    float a2 = (e2.x == 0) ? a0rep : prev[e2.x * B_ + b];
    float a3 = (e3.x == 0) ? a0rep : prev[e3.x * B_ + b];
    float x0 = xb[(size_t)e0.y * xstr];
    float x1 = xb[(size_t)e1.y * xstr];
    float x2 = xb[(size_t)e2.y * xstr];
    float x3 = xb[(size_t)e3.y * xstr];
    float v0 = a0 - totprev + __int_as_float(e0.z) + x0;
    float v1 = a1 - totprev + __int_as_float(e1.z) + x1;
    float v2 = a2 - totprev + __int_as_float(e2.z) + x2;
    float v3 = a3 - totprev + __int_as_float(e3.z) + x3;
    float nm0 = fmaxf(m0, v0);
    s0 = s0 * __expf(m0 - nm0) + __expf(v0 - nm0);
    m0 = nm0;
    float nm1 = fmaxf(m1, v2);
    s1 = s1 * __expf(m1 - nm1) + __expf(v2 - nm1);
    m1 = nm1;
    nm0 = fmaxf(m0, v1);
    s0 = s0 * __expf(m0 - nm0) + __expf(v1 - nm0);
    m0 = nm0;
    nm1 = fmaxf(m1, v3);
    s1 = s1 * __expf(m1 - nm1) + __expf(v3 - nm1);
    m1 = nm1;
  }
  for (; i < he; ++i) {
    int4 e0 = epack[i];
    float a0 = (e0.x == 0) ? a0rep : prev[e0.x * B_ + b];
    float v0 = a0 - totprev + __int_as_float(e0.z) + xb[(size_t)e0.y * xstr];
    float nm0 = fmaxf(m0, v0);
    s0 = s0 * __expf(m0 - nm0) + __expf(v0 - nm0);
    m0 = nm0;
  }
  // merge acc1 into acc0 (guard -inf - -inf = NaN)
  if (m1 > -INFINITY) {
    float mm = fmaxf(m0, m1);
    s0 = s0 * __expf(m0 - mm) + s1 * __expf(m1 - mm);
    m0 = mm;
  }
  // merge across the two halves of the wave
  {
    float om = __shfl_xor(m0, 32);
    float os = __shfl_xor(s0, 32);
    float mm = fmaxf(m0, om);
    if (mm > -INFINITY) {
      s0 = s0 * __expf(m0 - mm) + os * __expf(om - mm);
      m0 = mm;
    }
  }

  float nv = (s0 > 0.f) ? (m0 + __logf(s0)) : NEGV;   // pre-leak new[s,b]
  if (!half) next[s * B_ + b] = nv;
  float ev = (s0 > 0.f) ? s0 * __expf(m0) : 0.f;      // exp(nv), 0 on underflow

  // reduce exp(new) over the block's 4 states, then 1 bucketed atomic per (block,b)
  if (!half) wsum[wv][b] = ev;
  __syncthreads();
  if (threadIdx.x < 32) {
    float tt = wsum[0][b] + wsum[1][b] + wsum[2][b] + wsum[3][b];
    atomicAdd(&totsumP[(size_t)(t + 1) * B_ * NBUCK + b * NBUCK + g], tt);
  }
}

// ---------------- epilogue kernels ----------------
// final_kernel: sum exp(alphaT_norm + flw) into bucketed finalsum[b][g]
__global__ __launch_bounds__(256) void final_kernel(
    const float* __restrict__ buf, const float* __restrict__ totsumP,
    const float* __restrict__ flw, float* __restrict__ finalsum) {
  const int b  = threadIdx.x & 31;
  const int j  = threadIdx.x >> 5;                 // 0..7 (half-wave -> state)
  const int s  = blockIdx.x * SPB_F + j;           // 500*8 = 4000 exactly
  const int wv = threadIdx.x >> 6;
  const int g  = blockIdx.x & (NBUCK - 1);
  __shared__ float wsum[4][32];

  const float4* tp = (const float4*)(totsumP + (size_t)T_ * B_ * NBUCK + b * NBUCK);
  float4 q0 = tp[0], q1 = tp[1], q2 = tp[2], q3 = tp[3];
  float tsum = (q0.x + q0.y + q0.z + q0.w) + (q1.x + q1.y + q1.z + q1.w) +
               (q2.x + q2.y + q2.z + q2.w) + (q3.x + q3.y + q3.z + q3.w);
  const float totlast = logf(tsum);

  const float* __restrict__ last = buf + (size_t)(T_ & 1) * S_ * B_;
  float v = last[s * B_ + b];
  if (s == 0) v = logaddexpf_(v, LOGLEAK + totlast);
  v = v - totlast + flw[s];
  float ev = __expf(v);
  float evs = ev + __shfl_xor(ev, 32);             // merge the wave's 2 states
  if ((threadIdx.x & 63) < 32) wsum[wv][b] = evs;
  __syncthreads();
  if (threadIdx.x < 32) {
    float tt = wsum[0][b] + wsum[1][b] + wsum[2][b] + wsum[3][b];
    atomicAdd(&finalsum[b * NBUCK + g], tt);
  }
}

// loss_kernel: logz_b = sum_t log(tot_t); den_b = logz_b + log(finalsum_b); loss.
__global__ __launch_bounds__(1024) void loss_kernel(
    const float* __restrict__ totsumP, const float* __restrict__ finalsum,
    const float* __restrict__ numsum, float* __restrict__ out) {
  __shared__ float part[32][32];
  const int b  = threadIdx.x & 31;
  const int tt = threadIdx.x >> 5;   // 0..31
  float partial = 0.f;
  for (int idx = 1 + tt; idx <= T_; idx += 32) {
    const float4* tp = (const float4*)(totsumP + (size_t)idx * B_ * NBUCK + b * NBUCK);
    float4 q0 = tp[0], q1 = tp[1], q2 = tp[2], q3 = tp[3];
    float tsum = (q0.x + q0.y + q0.z + q0.w) + (q1.x + q1.y + q1.z + q1.w) +
                 (q2.x + q2.y + q2.z + q2.w) + (q3.x + q3.y + q3.z + q3.w);
    partial += logf(tsum);
  }
  part[tt][b] = partial;
  __syncthreads();
  if (threadIdx.x < 32) {
    float logz = 0.f;
    for (int k = 0; k < 32; ++k) logz += part[k][b];
    const float4* fp = (const float4*)(finalsum + b * NBUCK);
    float4 f0 = fp[0], f1 = fp[1], f2 = fp[2], f3 = fp[3];
    float fsum = (f0.x + f0.y + f0.z + f0.w) + (f1.x + f1.y + f1.z + f1.w) +
                 (f2.x + f2.y + f2.z + f2.w) + (f3.x + f3.y + f3.z + f3.w);
    float den_b = logz + logf(fsum);
    for (int off = 16; off; off >>= 1) den_b += __shfl_down(den_b, off);
    if (threadIdx.x == 0) {
      out[0] = -(numsum[0] - den_b) / (float)(B_ * T_);
    }
  }
}

// ---------------- launcher ----------------

extern "C" void kernel_launch(void* const* d_in, const int* in_sizes, int n_in,
                              void* d_out, int out_size, void* d_ws, size_t ws_size,
                              hipStream_t stream) {
  const float* x      = (const float*)d_in[0];
  const int*   target = (const int*)d_in[1];
  const int*   esrc   = (const int*)d_in[2];
  const int*   edst   = (const int*)d_in[3];
  const int*   epdf   = (const int*)d_in[4];
  const float* ew     = (const float*)d_in[5];
  const float* flw    = (const float*)d_in[6];
  float* out = (float*)d_out;

  char* base = (char*)d_ws;
  size_t off = 0;
  auto take = [&](size_t bytes) -> char* {
    char* r = base + off;
    off += (bytes + 255) & ~(size_t)255;
    return r;
  };
  float* buf      = (float*)take((size_t)2 * S_ * B_ * 4);          // double-buffered alpha
  float* totsumP  = (float*)take((size_t)(T_ + 1) * B_ * NBUCK * 4);// bucketed sum(exp(new_t))
  float* finalsum = (float*)take(1024 * 4);
  float* numsum   = (float*)take(256);
  int*   indeg    = (int*)take((size_t)S_ * 4);
  int*   row_off  = (int*)take((size_t)(S_ + 1) * 4);
  int*   fill     = (int*)take((size_t)S_ * 4);
  int4*  epack    = (int4*)take((size_t)E_ * 16);                   // CSR-by-dst packed arcs
  size_t xt_bytes = (size_t)T_ * D_ * B_ * 4;
  int use_xt = (off + xt_bytes <= ws_size) ? 1 : 0;                 // deterministic per ws_size
  float* xT = (float*)take(xt_bytes);
  const float* xsrc = use_xt ? (const float*)xT : x;

  int init_n = (T_ + 1) * B_ * NBUCK;
  if (init_n < S_ * B_) init_n = S_ * B_;
  hipLaunchKernelGGL(init_kernel, dim3((init_n + 255) / 256), dim3(256), 0, stream,
                     buf, totsumP, finalsum, numsum, indeg);
  hipLaunchKernelGGL(hist_kernel, dim3((E_ + 255) / 256), dim3(256), 0, stream, edst, indeg);
  hipLaunchKernelGGL(scan_kernel, dim3(1), dim3(1024), 0, stream, indeg, row_off, fill);
  hipLaunchKernelGGL(scatter_kernel, dim3((E_ + 255) / 256), dim3(256), 0, stream,
                     esrc, edst, epdf, ew, fill, epack);
  if (use_xt) {
    hipLaunchKernelGGL(transpose_kernel, dim3(D_ / 32, T_), dim3(256), 0, stream, x, xT);
  }
  hipLaunchKernelGGL(num_kernel, dim3((B_ * T_ + 255) / 256), dim3(256), 0, stream,
                     x, target, numsum);

  for (int t = 0; t < T_; ++t) {
    hipLaunchKernelGGL(step_kernel, dim3(NBLK), dim3(256), 0, stream,
                       xsrc, epack, row_off, buf, totsumP, use_xt, t);
  }
  hipLaunchKernelGGL(final_kernel, dim3(NBLK_F), dim3(256), 0, stream,
                     buf, totsumP, flw, finalsum);
  hipLaunchKernelGGL(loss_kernel, dim3(1), dim3(1024), 0, stream,
                     totsumP, finalsum, numsum, out);
}